// Round 12
// baseline (176.628 us; speedup 1.0000x reference)
//
#include <hip/hip_runtime.h>
#include <hip/hip_bf16.h>

// GRU: B=4096, T=512, I=1, H=32, C=2.
// One 32-lane group per batch element (8 groups / 256-thr block, 2048 waves).
// Lane j owns h[j] and W_hh rows {j,32+j,64+j} as 48 int-packed fp16x2 regs.
// R11: the 48 dots are explicit inline-asm v_dot2_f32_f16 (16 blocks x 3),
// forcing (a) exactly-48-instruction dot chain, (b) true VGPR residency of
// the weight packs (asm "v" inputs each iteration are not rematerializable).
// Transcendentals stay native v_exp/v_rcp; x staged wholly in LDS.

typedef _Float16 half2v __attribute__((ext_vector_type(2)));

__device__ __forceinline__ int pkf16(float lo, float hi) {
    return __builtin_bit_cast(int, __builtin_amdgcn_cvt_pkrtz(lo, hi));
}

// sigmoid(a) = 1/(1+exp(-a)) : mul + exp2 + add + rcp (no IEEE div lowering)
__device__ __forceinline__ float sigm(float a) {
    float e = __builtin_amdgcn_exp2f(a * -1.442695041f);
    return __builtin_amdgcn_rcpf(1.0f + e);
}

#define FOR16(M) M(0) M(1) M(2) M(3) M(4) M(5) M(6) M(7) \
                 M(8) M(9) M(10) M(11) M(12) M(13) M(14) M(15)

__global__ __launch_bounds__(256, 2)
void gru_fused_kernel(const float* __restrict__ x,
                      const float* __restrict__ W_ih,
                      const float* __restrict__ W_hh,
                      const float* __restrict__ b_ih,
                      const float* __restrict__ b_hh,
                      const float* __restrict__ fc_w,
                      const float* __restrict__ fc_b,
                      float* __restrict__ out)
{
    const int tid = threadIdx.x;
    const int j   = tid & 31;                      // hidden index this lane owns
    const int g   = tid >> 5;                      // group (batch slot in block)
    const int bb  = blockIdx.x * 8 + g;            // batch element

    __shared__ float xs[8 * 516];                  // all x for this block (pad 4)
    __shared__ unsigned short hbuf[8][32];         // f16 h per group (64B rows)

    // ---- stage the block's entire x [8 batches x 512 t] into LDS ----
    {
        const float* xbase = x + (size_t)blockIdx.x * 8 * 512;
        #pragma unroll
        for (int k = 0; k < 16; ++k) {
            int idx = tid + k * 256;               // coalesced
            int b   = idx >> 9, p = idx & 511;
            xs[b * 516 + p] = xbase[idx];
        }
    }

    // ---- named packed weight registers (48 ints) ----
#define DECLW(p) int wr##p, wz##p, wn##p;
    FOR16(DECLW)
#undef DECLW

    {
        const float4* wrp = reinterpret_cast<const float4*>(W_hh + (j) * 32);
        const float4* wzp = reinterpret_cast<const float4*>(W_hh + (32 + j) * 32);
        const float4* wnp = reinterpret_cast<const float4*>(W_hh + (64 + j) * 32);
#define INITQ(q, p0, p1)                                \
        {                                               \
            float4 a = wrp[q], b = wzp[q], c = wnp[q];  \
            wr##p0 = pkf16(a.x, a.y);                   \
            wr##p1 = pkf16(a.z, a.w);                   \
            wz##p0 = pkf16(b.x, b.y);                   \
            wz##p1 = pkf16(b.z, b.w);                   \
            wn##p0 = pkf16(c.x, c.y);                   \
            wn##p1 = pkf16(c.z, c.w);                   \
        }
        INITQ(0, 0, 1)  INITQ(1, 2, 3)  INITQ(2, 4, 5)  INITQ(3, 6, 7)
        INITQ(4, 8, 9)  INITQ(5, 10, 11) INITQ(6, 12, 13) INITQ(7, 14, 15)
#undef INITQ
    }

    // biases / input weights (I == 1)
    const float br   = b_ih[j]      + b_hh[j];
    const float bz   = b_ih[32 + j] + b_hh[32 + j];
    const float bin  = b_ih[64 + j];
    const float bhn  = b_hh[64 + j];
    const float wihr = W_ih[j];
    const float wihz = W_ih[32 + j];
    const float wihn = W_ih[64 + j];

    float h = 0.0f;
    hbuf[g][j] = 0;                     // f16 +0.0
    __syncthreads();                    // x staging crosses waves

    // three dots (r,z,n gates) for one k-pair pack, as explicit ISA
#define DOT3(WP, ZP, NP, HPK)                                   \
    asm("v_dot2_f32_f16 %0, %3, %6, %0\n\t"                     \
        "v_dot2_f32_f16 %1, %4, %6, %1\n\t"                     \
        "v_dot2_f32_f16 %2, %5, %6, %2"                         \
        : "+v"(ar), "+v"(az), "+v"(an)                          \
        : "v"(WP), "v"(ZP), "v"(NP), "v"(HPK));

    for (int c = 0; c < 16; ++c) {
        const float* xc = &xs[g * 516 + c * 32];

        #pragma unroll
        for (int tt = 0; tt < 32; ++tt) {
            float xb = xc[tt];                       // ds_read_b32, imm offset

            // read the whole replicated h row (4 x b128 broadcast reads)
            const int4* hp = reinterpret_cast<const int4*>(&hbuf[g][0]);
            int4 A = hp[0], B = hp[1], C = hp[2], D = hp[3];

            float ar = fmaf(xb, wihr, br);
            float az = fmaf(xb, wihz, bz);
            float an = bhn;

            DOT3(wr0,  wz0,  wn0,  A.x)
            DOT3(wr1,  wz1,  wn1,  A.y)
            DOT3(wr2,  wz2,  wn2,  A.z)
            DOT3(wr3,  wz3,  wn3,  A.w)
            DOT3(wr4,  wz4,  wn4,  B.x)
            DOT3(wr5,  wz5,  wn5,  B.y)
            DOT3(wr6,  wz6,  wn6,  B.z)
            DOT3(wr7,  wz7,  wn7,  B.w)
            DOT3(wr8,  wz8,  wn8,  C.x)
            DOT3(wr9,  wz9,  wn9,  C.y)
            DOT3(wr10, wz10, wn10, C.z)
            DOT3(wr11, wz11, wn11, C.w)
            DOT3(wr12, wz12, wn12, D.x)
            DOT3(wr13, wz13, wn13, D.y)
            DOT3(wr14, wz14, wn14, D.z)
            DOT3(wr15, wz15, wn15, D.w)

            float r = sigm(ar);
            float z = sigm(az);
            float npre = fmaf(r, an, fmaf(xb, wihn, bin));
            // tanh(a) = 1 - 2/(1+exp(2a)), exp via exp2, div via rcp
            float e2 = __builtin_amdgcn_exp2f(npre * 2.885390082f);
            float t  = __builtin_amdgcn_rcpf(1.0f + e2);
            float n  = fmaf(-2.0f, t, 1.0f);
            h = fmaf(z, h - n, n);       // h = n + z*(h-n)

            // publish new h as f16 for next step's broadcast reads
            hbuf[g][j] = __builtin_bit_cast(unsigned short, (_Float16)h);
        }
    }
#undef DOT3

    // ---- FC epilogue: out[bb, c] = sum_j h_j * fc_w[c*32+j] + fc_b[c] ----
    float s0 = h * fc_w[j];
    float s1 = h * fc_w[32 + j];
    #pragma unroll
    for (int off = 16; off >= 1; off >>= 1) {
        s0 += __shfl_xor(s0, off, 32);
        s1 += __shfl_xor(s1, off, 32);
    }
    if (j == 0) {
        out[(size_t)bb * 2 + 0] = s0 + fc_b[0];
        out[(size_t)bb * 2 + 1] = s1 + fc_b[1];
    }
}

extern "C" void kernel_launch(void* const* d_in, const int* in_sizes, int n_in,
                              void* d_out, int out_size, void* d_ws, size_t ws_size,
                              hipStream_t stream)
{
    const float* x    = (const float*)d_in[0];
    const float* W_ih = (const float*)d_in[1];
    const float* W_hh = (const float*)d_in[2];
    const float* b_ih = (const float*)d_in[3];
    const float* b_hh = (const float*)d_in[4];
    const float* fc_w = (const float*)d_in[5];
    const float* fc_b = (const float*)d_in[6];
    float* out = (float*)d_out;

    dim3 grid(512), block(256);
    hipLaunchKernelGGL(gru_fused_kernel, grid, block, 0, stream,
                       x, W_ih, W_hh, b_ih, b_hh, fc_w, fc_b, out);
}

// Round 13
// 170.730 us; speedup vs baseline: 1.0345x; 1.0345x over previous
//
#include <hip/hip_runtime.h>
#include <hip/hip_bf16.h>

// GRU: B=4096, T=512, I=1, H=32, C=2.
// R12: each 32-lane group processes TWO batch elements (interleaved chains).
// Weight packs (48 ints, j-indexed) are SHARED by both chains; the two
// dot/gate/LDS-roundtrip chains are independent -> instruction-level latency
// hiding inside one wave (R9/R11 showed ~29% unhidden stall with 2-wave TLP).
// Block 256 = 16 batches, grid 256 = 1 block/CU, 1024 waves = 1 wave/SIMD.
// Per-batch issue cost unchanged; stall share should convert to VALUBusy.

typedef _Float16 half2v __attribute__((ext_vector_type(2)));

__device__ __forceinline__ float fdot2f(int a, int b, float c) {
    return __builtin_amdgcn_fdot2(__builtin_bit_cast(half2v, a),
                                  __builtin_bit_cast(half2v, b), c, false);
}

__device__ __forceinline__ int pkf16(float lo, float hi) {
    return __builtin_bit_cast(int, __builtin_amdgcn_cvt_pkrtz(lo, hi));
}

// sigmoid via exp2+rcp (no IEEE div); tanh via exp2+rcp
__device__ __forceinline__ float sigm(float a) {
    float e = __builtin_amdgcn_exp2f(a * -1.442695041f);
    return __builtin_amdgcn_rcpf(1.0f + e);
}

#define FOR16(M) M(0) M(1) M(2) M(3) M(4) M(5) M(6) M(7) \
                 M(8) M(9) M(10) M(11) M(12) M(13) M(14) M(15)

__global__ __launch_bounds__(256, 1)
void gru_fused_kernel(const float* __restrict__ x,
                      const float* __restrict__ W_ih,
                      const float* __restrict__ W_hh,
                      const float* __restrict__ b_ih,
                      const float* __restrict__ b_hh,
                      const float* __restrict__ fc_w,
                      const float* __restrict__ fc_b,
                      float* __restrict__ out)
{
    const int tid = threadIdx.x;
    const int j   = tid & 31;                      // hidden index this lane owns
    const int g   = tid >> 5;                      // group 0..7
    const int b0  = 2 * g;                         // local batch slots
    const int b1  = 2 * g + 1;

    __shared__ float xs[16 * 516];                 // x for 16 batches (pad 4)
    __shared__ unsigned short hbuf[16][32];        // f16 h per local batch

    // ---- stage the block's entire x [16 batches x 512 t] into LDS ----
    {
        const float* xbase = x + (size_t)blockIdx.x * 16 * 512;
        #pragma unroll
        for (int k = 0; k < 32; ++k) {
            int idx = tid + k * 256;               // coalesced
            int b   = idx >> 9, p = idx & 511;
            xs[b * 516 + p] = xbase[idx];
        }
    }

    // ---- named packed weight registers (48 ints, shared by both chains) ----
#define DECLW(p) int wr##p, wz##p, wn##p;
    FOR16(DECLW)
#undef DECLW

    {
        const float4* wrp = reinterpret_cast<const float4*>(W_hh + (j) * 32);
        const float4* wzp = reinterpret_cast<const float4*>(W_hh + (32 + j) * 32);
        const float4* wnp = reinterpret_cast<const float4*>(W_hh + (64 + j) * 32);
#define INITQ(q, p0, p1)                                \
        {                                               \
            float4 a = wrp[q], b = wzp[q], c = wnp[q];  \
            wr##p0 = pkf16(a.x, a.y);                   \
            wr##p1 = pkf16(a.z, a.w);                   \
            wz##p0 = pkf16(b.x, b.y);                   \
            wz##p1 = pkf16(b.z, b.w);                   \
            wn##p0 = pkf16(c.x, c.y);                   \
            wn##p1 = pkf16(c.z, c.w);                   \
        }
        INITQ(0, 0, 1)  INITQ(1, 2, 3)  INITQ(2, 4, 5)  INITQ(3, 6, 7)
        INITQ(4, 8, 9)  INITQ(5, 10, 11) INITQ(6, 12, 13) INITQ(7, 14, 15)
#undef INITQ
    }

    // biases / input weights (I == 1)
    const float br   = b_ih[j]      + b_hh[j];
    const float bz   = b_ih[32 + j] + b_hh[32 + j];
    const float bin  = b_ih[64 + j];
    const float bhn  = b_hh[64 + j];
    const float wihr = W_ih[j];
    const float wihz = W_ih[32 + j];
    const float wihn = W_ih[64 + j];

    float h0 = 0.0f, h1 = 0.0f;
    hbuf[b0][j] = 0;
    hbuf[b1][j] = 0;
    __syncthreads();                    // x staging crosses waves

    const float* xc0 = &xs[b0 * 516];
    const float* xc1 = &xs[b1 * 516];

    for (int c = 0; c < 16; ++c) {
        #pragma unroll 8
        for (int tt = 0; tt < 32; ++tt) {
            const int t = c * 32 + tt;
            float xb0 = xc0[t];                      // ds_read_b32 broadcast
            float xb1 = xc1[t];

            const int4* hp0 = reinterpret_cast<const int4*>(&hbuf[b0][0]);
            const int4* hp1 = reinterpret_cast<const int4*>(&hbuf[b1][0]);
            int4 A0 = hp0[0], B0 = hp0[1], C0 = hp0[2], D0 = hp0[3];
            int4 A1 = hp1[0], B1 = hp1[1], C1 = hp1[2], D1 = hp1[3];

            float ar0 = fmaf(xb0, wihr, br), ar1 = fmaf(xb1, wihr, br);
            float az0 = fmaf(xb0, wihz, bz), az1 = fmaf(xb1, wihz, bz);
            float an0 = bhn,                 an1 = bhn;

#define D2(P, HK0, HK1)                                            \
            ar0 = fdot2f(wr##P, HK0, ar0); ar1 = fdot2f(wr##P, HK1, ar1); \
            az0 = fdot2f(wz##P, HK0, az0); az1 = fdot2f(wz##P, HK1, az1); \
            an0 = fdot2f(wn##P, HK0, an0); an1 = fdot2f(wn##P, HK1, an1);
            D2(0,  A0.x, A1.x)  D2(1,  A0.y, A1.y)
            D2(2,  A0.z, A1.z)  D2(3,  A0.w, A1.w)
            D2(4,  B0.x, B1.x)  D2(5,  B0.y, B1.y)
            D2(6,  B0.z, B1.z)  D2(7,  B0.w, B1.w)
            D2(8,  C0.x, C1.x)  D2(9,  C0.y, C1.y)
            D2(10, C0.z, C1.z)  D2(11, C0.w, C1.w)
            D2(12, D0.x, D1.x)  D2(13, D0.y, D1.y)
            D2(14, D0.z, D1.z)  D2(15, D0.w, D1.w)
#undef D2

            float r0 = sigm(ar0), r1 = sigm(ar1);
            float z0 = sigm(az0), z1 = sigm(az1);
            float np0 = fmaf(r0, an0, fmaf(xb0, wihn, bin));
            float np1 = fmaf(r1, an1, fmaf(xb1, wihn, bin));
            float e0 = __builtin_amdgcn_exp2f(np0 * 2.885390082f);
            float e1 = __builtin_amdgcn_exp2f(np1 * 2.885390082f);
            float t0 = __builtin_amdgcn_rcpf(1.0f + e0);
            float t1 = __builtin_amdgcn_rcpf(1.0f + e1);
            float n0 = fmaf(-2.0f, t0, 1.0f);
            float n1 = fmaf(-2.0f, t1, 1.0f);
            h0 = fmaf(z0, h0 - n0, n0);
            h1 = fmaf(z1, h1 - n1, n1);

            hbuf[b0][j] = __builtin_bit_cast(unsigned short, (_Float16)h0);
            hbuf[b1][j] = __builtin_bit_cast(unsigned short, (_Float16)h1);
        }
    }

    // ---- FC epilogue for both batches ----
    const float f0 = fc_w[j], f1 = fc_w[32 + j];
    float s00 = h0 * f0, s01 = h0 * f1;
    float s10 = h1 * f0, s11 = h1 * f1;
    #pragma unroll
    for (int off = 16; off >= 1; off >>= 1) {
        s00 += __shfl_xor(s00, off, 32);
        s01 += __shfl_xor(s01, off, 32);
        s10 += __shfl_xor(s10, off, 32);
        s11 += __shfl_xor(s11, off, 32);
    }
    if (j == 0) {
        const size_t gb0 = (size_t)blockIdx.x * 16 + b0;
        const size_t gb1 = (size_t)blockIdx.x * 16 + b1;
        out[gb0 * 2 + 0] = s00 + fc_b[0];
        out[gb0 * 2 + 1] = s01 + fc_b[1];
        out[gb1 * 2 + 0] = s10 + fc_b[0];
        out[gb1 * 2 + 1] = s11 + fc_b[1];
    }
}

extern "C" void kernel_launch(void* const* d_in, const int* in_sizes, int n_in,
                              void* d_out, int out_size, void* d_ws, size_t ws_size,
                              hipStream_t stream)
{
    const float* x    = (const float*)d_in[0];
    const float* W_ih = (const float*)d_in[1];
    const float* W_hh = (const float*)d_in[2];
    const float* b_ih = (const float*)d_in[3];
    const float* b_hh = (const float*)d_in[4];
    const float* fc_w = (const float*)d_in[5];
    const float* fc_b = (const float*)d_in[6];
    float* out = (float*)d_out;

    // 4096 batches / 16 per block = 256 blocks (1 per CU), 1 wave/SIMD
    dim3 grid(256), block(256);
    hipLaunchKernelGGL(gru_fused_kernel, grid, block, 0, stream,
                       x, W_ih, W_hh, b_ih, b_hh, fc_w, fc_b, out);
}